// Round 5
// baseline (85.095 us; speedup 1.0000x reference)
//
#include <hip/hip_runtime.h>
#include <hip/hip_bf16.h>
#include <math.h>

typedef unsigned short ushort_t;
typedef unsigned int uint_t;

#define C_CURV 1.5f
#define SQRT_C 1.22474487139158905f
#define TEMP_ 0.1f

typedef __attribute__((ext_vector_type(8))) short short8;
typedef __attribute__((ext_vector_type(4))) float f32x4;

static __device__ __forceinline__ ushort_t f2bf(float f) {
  union { float f; uint_t u; } v; v.f = f;
  uint_t u = v.u;
  uint_t r = (u + 0x7FFFu + ((u >> 16) & 1u)) >> 16;  // RNE fp32->bf16
  return (ushort_t)r;
}

static __device__ __forceinline__ float b2f(ushort_t h) {
  union { uint_t u; float f; } v; v.u = ((uint_t)h) << 16;
  return v.f;
}

static __device__ __forceinline__ float gelu_exact(float x) {
  return 0.5f * x * (1.0f + erff(x * 0.70710678118654752f));
}

#define GLOAD_LDS16(gp, lp) __builtin_amdgcn_global_load_lds( \
    (const __attribute__((address_space(1))) void*)(const void*)(gp), \
    (__attribute__((address_space(3))) void*)(void*)(lp), 16, 0, 0)

// ---------------- convert x (fp32) -> bf16 ----------------
__global__ void k_cvt_x(const float* __restrict__ x, ushort_t* __restrict__ xb, int n4) {
  int i = blockIdx.x * blockDim.x + threadIdx.x;
  if (i >= n4) return;
  float4 v = reinterpret_cast<const float4*>(x)[i];
  ushort4 o;
  o.x = f2bf(v.x); o.y = f2bf(v.y); o.z = f2bf(v.z); o.w = f2bf(v.w);
  reinterpret_cast<ushort4*>(xb)[i] = o;
}

// ---------------- GEMM: BN=256 x BK=32 tiles, 1KB-contiguous staging, ----------------
// ---------------- 4-buffer depth-3 pipeline with counted vmcnt (T3+T4) ----------------
// Block: 256 thr / 4 waves. Out: 64 batch rows x 256 n-cols (bf16 partial).
// Per tile per wave: 8x W-stage (1KB rows) + 1x A-stage = 9 vmem instr.
// Requires nt = kchunk/32 >= 4 (launcher guarantees).
__global__ __launch_bounds__(256) void k_gemm(
    const ushort_t* __restrict__ Abase, long a_br_stride,
    const float* __restrict__ Wg, const float* __restrict__ Ws,
    ushort_t* __restrict__ partial, int N, int K, int kchunk)
{
  __shared__ float    sW[4][32][256];   // 128 KB
  __shared__ ushort_t sA[4][64][32];    // 16 KB

  const int tn = blockIdx.x, ks = blockIdx.y, br = blockIdx.z;
  const int KS = gridDim.y;
  const ushort_t* A = Abase + (long)br * a_br_stride;
  const float* W = br ? Ws : Wg;
  const int lane = threadIdx.x & 63;
  const int w = threadIdx.x >> 6;
  const int c = lane & 15;
  const int g = lane >> 4;
  const int n0b = tn * 256;
  const int k0 = ks * kchunk;

  const float* wst = W + (long)(k0 + w * 8) * N + n0b + lane * 4;
  const ushort_t* ast = A + (long)(w * 16 + (lane >> 2)) * K + k0 + (lane & 3) * 8;

  f32x4 acc[4][4];  // [mi][nf]
  #pragma unroll
  for (int mi = 0; mi < 4; ++mi)
    #pragma unroll
    for (int nf = 0; nf < 4; ++nf) acc[mi][nf] = f32x4{0.f, 0.f, 0.f, 0.f};

#define STAGE(buf, t) do { \
    _Pragma("unroll") for (int i = 0; i < 8; ++i) \
      GLOAD_LDS16(wst + (long)((t) * 32 + i) * N, &sW[buf][w * 8 + i][0]); \
    GLOAD_LDS16(ast + (t) * 32, &sA[buf][w * 16][0]); \
  } while (0)

#define COMPUTE(buf) do { \
    short8 af[4]; \
    _Pragma("unroll") for (int mi = 0; mi < 4; ++mi) \
      af[mi] = *reinterpret_cast<const short8*>(&sA[buf][c + 16 * mi][8 * g]); \
    _Pragma("unroll") for (int nf = 0; nf < 4; ++nf) { \
      float bw[8]; \
      _Pragma("unroll") for (int j = 0; j < 8; ++j) \
        bw[j] = sW[buf][8 * g + j][w * 64 + nf * 16 + c]; \
      short8 bf; \
      _Pragma("unroll") for (int j = 0; j < 8; ++j) bf[j] = (short)f2bf(bw[j]); \
      _Pragma("unroll") for (int mi = 0; mi < 4; ++mi) \
        acc[mi][nf] = __builtin_amdgcn_mfma_f32_16x16x32_bf16(af[mi], bf, acc[mi][nf], 0, 0, 0); \
    } \
  } while (0)

  const int nt = kchunk >> 5;  // >= 4
  STAGE(0, 0);
  STAGE(1, 1);
  STAGE(2, 2);
  int t = 0;
  for (; t + 3 < nt; ++t) {
    asm volatile("s_waitcnt vmcnt(18)" ::: "memory");  // oldest stage (t) complete
    __builtin_amdgcn_s_barrier();
    STAGE((t + 3) & 3, t + 3);                          // overwrites buf (t-1)&3: readers passed barrier
    COMPUTE(t & 3);
  }
  // peeled tail: waits shrink as the stage stream ends
  asm volatile("s_waitcnt vmcnt(18)" ::: "memory");
  __builtin_amdgcn_s_barrier();
  COMPUTE(t & 3); ++t;
  asm volatile("s_waitcnt vmcnt(9)" ::: "memory");
  __builtin_amdgcn_s_barrier();
  COMPUTE(t & 3); ++t;
  asm volatile("s_waitcnt vmcnt(0)" ::: "memory");
  __builtin_amdgcn_s_barrier();
  COMPUTE(t & 3);
#undef STAGE
#undef COMPUTE

  // D layout (m89-verified): col = lane&15, row = 4*(lane>>4) + reg. bf16 partial store.
  ushort_t* po = partial + (long)(br * KS + ks) * 64 * N;
  #pragma unroll
  for (int mi = 0; mi < 4; ++mi)
    #pragma unroll
    for (int nf = 0; nf < 4; ++nf)
      #pragma unroll
      for (int q = 0; q < 4; ++q) {
        int b = 16 * mi + 4 * g + q;
        po[(long)b * N + n0b + w * 64 + nf * 16 + c] = f2bf(acc[mi][nf][q]);
      }
}

// ---------------- reduce bf16 K-split partials + bias + exact GELU -> bf16 activations ----------------
__global__ void k_reduce_gelu(const ushort_t* __restrict__ partial,
    const float* __restrict__ bg, const float* __restrict__ bs,
    ushort_t* __restrict__ hb, int N, int KS, int total8)
{
  int i = blockIdx.x * blockDim.x + threadIdx.x;
  if (i >= total8) return;
  int perbr8 = 64 * N / 8;
  int br = i / perbr8;
  int rem = i - br * perbr8;
  const short8* pp = reinterpret_cast<const short8*>(partial) + (long)br * KS * perbr8 + rem;
  float s[8] = {0.f, 0.f, 0.f, 0.f, 0.f, 0.f, 0.f, 0.f};
  for (int ks = 0; ks < KS; ++ks) {
    short8 t = pp[(long)ks * perbr8];
    #pragma unroll
    for (int j = 0; j < 8; ++j) s[j] += b2f((ushort_t)t[j]);
  }
  int n8 = rem % (N / 8);
  float4 bv0 = reinterpret_cast<const float4*>(br ? bs : bg)[n8 * 2];
  float4 bv1 = reinterpret_cast<const float4*>(br ? bs : bg)[n8 * 2 + 1];
  s[0] += bv0.x; s[1] += bv0.y; s[2] += bv0.z; s[3] += bv0.w;
  s[4] += bv1.x; s[5] += bv1.y; s[6] += bv1.z; s[7] += bv1.w;
  short8 o;
  #pragma unroll
  for (int j = 0; j < 8; ++j) o[j] = (short)f2bf(gelu_exact(s[j]));
  reinterpret_cast<short8*>(hb)[i] = o;
}

// ---------------- layer-3 reduce (bf16 partials) + bias + expmap0 ----------------
__global__ __launch_bounds__(256) void k_expmap(const ushort_t* __restrict__ partial,
    const float* __restrict__ b3g, const float* __restrict__ b3s,
    ushort_t* __restrict__ hypb, float* __restrict__ y2, int KS)
{
  int b = blockIdx.x, br = blockIdx.y, d = threadIdx.x;
  const ushort_t* pp = partial + (long)(br * KS) * 64 * 256 + (long)b * 256 + d;
  float s = 0.f;
  #pragma unroll 8
  for (int ks = 0; ks < KS; ++ks) s += b2f(pp[(long)ks * 64 * 256]);
  s += (br ? b3s : b3g)[d];

  float v = s * s;
  #pragma unroll
  for (int off = 1; off < 64; off <<= 1) v += __shfl_xor(v, off);
  __shared__ float red[4];
  __shared__ float n2s;
  if ((threadIdx.x & 63) == 0) red[threadIdx.x >> 6] = v;
  __syncthreads();
  if (threadIdx.x == 0) n2s = red[0] + red[1] + red[2] + red[3];
  __syncthreads();
  float n = fmaxf(sqrtf(n2s), 1e-15f);
  float sn = SQRT_C * n;
  float t = tanhf(sn);
  float scale = t / sn;
  hypb[((long)br * 64 + b) * 256 + d] = f2bf(s * scale);
  if (threadIdx.x == 0) y2[br * 64 + b] = t * t / C_CURV;
}

// ---------------- Poincare distance logits (wave = 16 protos x 16 batch rows) ----------------
__global__ __launch_bounds__(256) void k_dist(const float* __restrict__ pg,
    const float* __restrict__ ps, const ushort_t* __restrict__ hypb,
    const float* __restrict__ y2, float* __restrict__ out)
{
  int u = blockIdx.x * 4 + (threadIdx.x >> 6);
  const int lane = threadIdx.x & 63;
  const int c = lane & 15, g = lane >> 4;
  const float* protos; const ushort_t* A; const float* y2p; float* ob; int P;
  if (u < 128) {
    protos = pg; P = 500; A = hypb; y2p = y2; ob = out;
  } else {
    u -= 128;
    if (u >= 1252) return;
    protos = ps; P = 5000; A = hypb + 64 * 256; y2p = y2 + 64; ob = out + 64 * 500;
  }
  const int w = u >> 2;    // proto tile
  const int mi = u & 3;    // 16-row slice of the batch
  int p = w * 16 + c;
  int pc = min(p, P - 1);
  const float* pp = protos + (long)pc * 256 + 8 * g;
  const ushort_t* ap = A + (long)(c + 16 * mi) * 256 + 8 * g;

  f32x4 acc = {0.f, 0.f, 0.f, 0.f};
  float x2p = 0.f;

  #pragma unroll
  for (int s8 = 0; s8 < 8; ++s8) {
    float4 v0 = *reinterpret_cast<const float4*>(pp + 32 * s8);
    float4 v1 = *reinterpret_cast<const float4*>(pp + 32 * s8 + 4);
    x2p += v0.x * v0.x + v0.y * v0.y + v0.z * v0.z + v0.w * v0.w
         + v1.x * v1.x + v1.y * v1.y + v1.z * v1.z + v1.w * v1.w;
    short8 bfr;
    bfr[0] = (short)f2bf(v0.x); bfr[1] = (short)f2bf(v0.y);
    bfr[2] = (short)f2bf(v0.z); bfr[3] = (short)f2bf(v0.w);
    bfr[4] = (short)f2bf(v1.x); bfr[5] = (short)f2bf(v1.y);
    bfr[6] = (short)f2bf(v1.z); bfr[7] = (short)f2bf(v1.w);
    short8 af = *reinterpret_cast<const short8*>(ap + 32 * s8);
    acc = __builtin_amdgcn_mfma_f32_16x16x32_bf16(af, bfr, acc, 0, 0, 0);
  }
  x2p += __shfl_xor(x2p, 16);
  x2p += __shfl_xor(x2p, 32);
  const float x2 = x2p;
  const float bb = 1.f - C_CURV * x2;
  const float LC = -2.f / (SQRT_C * TEMP_);

  if (p < P) {
    #pragma unroll
    for (int q = 0; q < 4; ++q) {
      int b = 16 * mi + 4 * g + q;
      float xy = -acc[q];
      float y2v = y2p[b];
      float a = 1.f + 2.f * C_CURV * xy + C_CURV * y2v;
      float den = fabsf(1.f + 2.f * C_CURV * xy + C_CURV * C_CURV * x2 * y2v);
      den = fmaxf(den, 1e-15f);
      float num2 = a * a * x2 + 2.f * a * bb * xy + bb * bb * y2v;
      num2 = fmaxf(num2, 0.f);
      float r = SQRT_C * sqrtf(num2) / den;
      r = fminf(r, 1.f - 1e-5f);
      r = fmaxf(r, 0.f);
      ob[(long)b * P + p] = LC * atanhf(r);
    }
  }
}

// ---------------- launch ----------------
extern "C" void kernel_launch(void* const* d_in, const int* in_sizes, int n_in,
                              void* d_out, int out_size, void* d_ws, size_t ws_size,
                              hipStream_t stream) {
  const float* x   = (const float*)d_in[0];
  const float* pg  = (const float*)d_in[1];
  const float* ps  = (const float*)d_in[2];
  const float* w1g = (const float*)d_in[3];
  const float* b1g = (const float*)d_in[4];
  const float* w2g = (const float*)d_in[5];
  const float* b2g = (const float*)d_in[6];
  const float* w3g = (const float*)d_in[7];
  const float* b3g = (const float*)d_in[8];
  const float* w1s = (const float*)d_in[9];
  const float* b1s = (const float*)d_in[10];
  const float* w2s = (const float*)d_in[11];
  const float* b2s = (const float*)d_in[12];
  const float* w3s = (const float*)d_in[13];
  const float* b3s = (const float*)d_in[14];
  float* out = (float*)d_out;
  char* ws = (char*)d_ws;
  (void)in_sizes; (void)n_in; (void)out_size; (void)ws_size;

  // K-splits: kchunk multiple of 32, nt = kchunk/32 >= 4.
  // L1: 768/6 = 128 (nt=4); L2: 4096/8 = 512 (nt=16); L3: 4096/32 = 128 (nt=4).
  const int KS1 = 6, KS2 = 8, KS3 = 32;
  // bf16 partials: max footprint = KS2*2*64*4096*2B = 8.39 MB
  size_t PART = (size_t)KS2 * 2 * 64 * 4096 * 2;

  ushort_t* partial = (ushort_t*)(ws);
  ushort_t* xb      = (ushort_t*)(ws + PART);
  ushort_t* h1b     = (ushort_t*)(ws + PART + 98304);
  ushort_t* h2b     = (ushort_t*)(ws + PART + 98304 + 1048576);
  ushort_t* hypb    = (ushort_t*)(ws + PART + 98304 + 2097152);
  float*    y2      = (float*)   (ws + PART + 98304 + 2097152 + 65536);

  // x -> bf16
  k_cvt_x<<<48, 256, 0, stream>>>(x, xb, 64 * 768 / 4);
  // layer 1: (64x768)@(768x4096)
  k_gemm<<<dim3(16, KS1, 2), 256, 0, stream>>>(xb, 0L, w1g, w1s, partial, 4096, 768, 768 / KS1);
  k_reduce_gelu<<<256, 256, 0, stream>>>(partial, b1g, b1s, h1b, 4096, KS1, 2 * 64 * 4096 / 8);
  // layer 2: (64x4096)@(4096x4096)
  k_gemm<<<dim3(16, KS2, 2), 256, 0, stream>>>(h1b, (long)64 * 4096, w2g, w2s, partial, 4096, 4096, 4096 / KS2);
  k_reduce_gelu<<<256, 256, 0, stream>>>(partial, b2g, b2s, h2b, 4096, KS2, 2 * 64 * 4096 / 8);
  // layer 3: (64x4096)@(4096x256)
  k_gemm<<<dim3(1, KS3, 2), 256, 0, stream>>>(h2b, (long)64 * 4096, w3g, w3s, partial, 256, 4096, 4096 / KS3);
  // reduce + bias + expmap0 -> hyp bf16, y2
  k_expmap<<<dim3(64, 2), 256, 0, stream>>>(partial, b3g, b3s, hypb, y2, KS3);
  // poincare distances -> logits
  k_dist<<<345, 256, 0, stream>>>(pg, ps, hypb, y2, out);
}

// Round 6
// 71.624 us; speedup vs baseline: 1.1881x; 1.1881x over previous
//
#include <hip/hip_runtime.h>
#include <hip/hip_bf16.h>
#include <math.h>

typedef unsigned short ushort_t;
typedef unsigned int uint_t;

#define C_CURV 1.5f
#define SQRT_C 1.22474487139158905f
#define TEMP_ 0.1f

typedef __attribute__((ext_vector_type(8))) short short8;
typedef __attribute__((ext_vector_type(4))) float f32x4;

static __device__ __forceinline__ ushort_t f2bf(float f) {
  union { float f; uint_t u; } v; v.f = f;
  uint_t u = v.u;
  uint_t r = (u + 0x7FFFu + ((u >> 16) & 1u)) >> 16;  // RNE fp32->bf16
  return (ushort_t)r;
}

static __device__ __forceinline__ float b2f(ushort_t h) {
  union { uint_t u; float f; } v; v.u = ((uint_t)h) << 16;
  return v.f;
}

static __device__ __forceinline__ float gelu_exact(float x) {
  return 0.5f * x * (1.0f + erff(x * 0.70710678118654752f));
}

#define GLOAD_LDS16(gp, lp) __builtin_amdgcn_global_load_lds( \
    (const __attribute__((address_space(1))) void*)(const void*)(gp), \
    (__attribute__((address_space(3))) void*)(void*)(lp), 16, 0, 0)

// ---------------- convert x (fp32) -> bf16 ----------------
__global__ void k_cvt_x(const float* __restrict__ x, ushort_t* __restrict__ xb, int n4) {
  int i = blockIdx.x * blockDim.x + threadIdx.x;
  if (i >= n4) return;
  float4 v = reinterpret_cast<const float4*>(x)[i];
  ushort4 o;
  o.x = f2bf(v.x); o.y = f2bf(v.y); o.z = f2bf(v.z); o.w = f2bf(v.w);
  reinterpret_cast<ushort4*>(xb)[i] = o;
}

// ---------------- GEMM: 512 thr / 8 waves, BN=128 x BK=32, 3-buffer depth-2, ----------------
// ---------------- 2 blocks/CU -> 16 staging waves/CU (wave-count = the BW lever) ----------
// Per tile per wave: 2x W-stage (2x512B rows each); waves 0-3 add 1x A-stage.
// Counted vmcnt is wave-role-dependent (3 vs 2). nt = kchunk/32 >= 3.
// k-map kappa(g,j) = 8g+j for A and B fragments (consistent bijection).
__global__ __launch_bounds__(512, 4) void k_gemm(
    const ushort_t* __restrict__ Abase, long a_br_stride,
    const float* __restrict__ Wg, const float* __restrict__ Ws,
    ushort_t* __restrict__ partial, int N, int K, int kchunk)
{
  __shared__ float    sW[3][32][128];   // 48 KB
  __shared__ ushort_t sA[3][64][32];    // 12 KB

  const int tn = blockIdx.x, ks = blockIdx.y, br = blockIdx.z;
  const int KS = gridDim.y;
  const ushort_t* A = Abase + (long)br * a_br_stride;
  const float* W = br ? Ws : Wg;
  const int lane = threadIdx.x & 63;
  const int w = threadIdx.x >> 6;   // 0..7
  const int c = lane & 15;
  const int g = lane >> 4;
  const int n0b = tn * 128;
  const int k0 = ks * kchunk;
  const bool hasA = (w < 4);

  // W staging: wave w, instr i in {0,1}: row k0 + w*4 + i*2 + (lane>>5), col n0b + (lane&31)*4
  const float* wst = W + (long)(k0 + w * 4 + (lane >> 5)) * N + n0b + (lane & 31) * 4;
  // A staging (waves 0-3): row w*16 + (lane>>2), col k0 + (lane&3)*8
  const ushort_t* ast = A + (long)(w * 16 + (lane >> 2)) * K + k0 + (lane & 3) * 8;

  f32x4 acc[4];
  #pragma unroll
  for (int mi = 0; mi < 4; ++mi) acc[mi] = f32x4{0.f, 0.f, 0.f, 0.f};

#define STAGE(buf, t) do { \
    GLOAD_LDS16(wst + (long)((t) * 32) * N,     &sW[buf][w * 4][0]); \
    GLOAD_LDS16(wst + (long)((t) * 32 + 2) * N, &sW[buf][w * 4 + 2][0]); \
    if (hasA) GLOAD_LDS16(ast + (t) * 32, &sA[buf][w * 16][0]); \
  } while (0)

#define COMPUTE(buf) do { \
    short8 af[4]; \
    _Pragma("unroll") for (int mi = 0; mi < 4; ++mi) \
      af[mi] = *reinterpret_cast<const short8*>(&sA[buf][c + 16 * mi][8 * g]); \
    float bw[8]; \
    _Pragma("unroll") for (int j = 0; j < 8; ++j) \
      bw[j] = sW[buf][8 * g + j][w * 16 + c]; \
    short8 bf; \
    _Pragma("unroll") for (int j = 0; j < 8; ++j) bf[j] = (short)f2bf(bw[j]); \
    _Pragma("unroll") for (int mi = 0; mi < 4; ++mi) \
      acc[mi] = __builtin_amdgcn_mfma_f32_16x16x32_bf16(af[mi], bf, acc[mi], 0, 0, 0); \
  } while (0)

  const int nt = kchunk >> 5;  // >= 3
  STAGE(0, 0);
  STAGE(1, 1);
  int t = 0;
  for (; t < nt - 1; ++t) {
    // wait: own stage(t) complete, stage(t+1) may stay in flight
    if (hasA) asm volatile("s_waitcnt vmcnt(3)" ::: "memory");
    else      asm volatile("s_waitcnt vmcnt(2)" ::: "memory");
    __builtin_amdgcn_s_barrier();
    if (t + 2 < nt) STAGE((t + 2) % 3, t + 2);  // overwrites buf (t-1)%3: readers passed barrier
    COMPUTE(t % 3);
  }
  asm volatile("s_waitcnt vmcnt(0)" ::: "memory");  // final tile: drain once
  __builtin_amdgcn_s_barrier();
  COMPUTE(t % 3);
#undef STAGE
#undef COMPUTE

  // D layout (m89-verified): col = lane&15, row = 4*(lane>>4) + reg. bf16 partial store.
  ushort_t* po = partial + (long)(br * KS + ks) * 64 * N;
  const int n0 = n0b + w * 16 + c;
  #pragma unroll
  for (int mi = 0; mi < 4; ++mi)
    #pragma unroll
    for (int q = 0; q < 4; ++q) {
      int b = 16 * mi + 4 * g + q;
      po[(long)b * N + n0] = f2bf(acc[mi][q]);
    }
}

// ---------------- reduce bf16 K-split partials + bias + exact GELU -> bf16 activations ----------------
__global__ void k_reduce_gelu(const ushort_t* __restrict__ partial,
    const float* __restrict__ bg, const float* __restrict__ bs,
    ushort_t* __restrict__ hb, int N, int KS, int total8)
{
  int i = blockIdx.x * blockDim.x + threadIdx.x;
  if (i >= total8) return;
  int perbr8 = 64 * N / 8;
  int br = i / perbr8;
  int rem = i - br * perbr8;
  const short8* pp = reinterpret_cast<const short8*>(partial) + (long)br * KS * perbr8 + rem;
  float s[8] = {0.f, 0.f, 0.f, 0.f, 0.f, 0.f, 0.f, 0.f};
  for (int ks = 0; ks < KS; ++ks) {
    short8 t = pp[(long)ks * perbr8];
    #pragma unroll
    for (int j = 0; j < 8; ++j) s[j] += b2f((ushort_t)t[j]);
  }
  int n8 = rem % (N / 8);
  float4 bv0 = reinterpret_cast<const float4*>(br ? bs : bg)[n8 * 2];
  float4 bv1 = reinterpret_cast<const float4*>(br ? bs : bg)[n8 * 2 + 1];
  s[0] += bv0.x; s[1] += bv0.y; s[2] += bv0.z; s[3] += bv0.w;
  s[4] += bv1.x; s[5] += bv1.y; s[6] += bv1.z; s[7] += bv1.w;
  short8 o;
  #pragma unroll
  for (int j = 0; j < 8; ++j) o[j] = (short)f2bf(gelu_exact(s[j]));
  reinterpret_cast<short8*>(hb)[i] = o;
}

// ---------------- layer-3 reduce (bf16 partials) + bias + expmap0 ----------------
__global__ __launch_bounds__(256) void k_expmap(const ushort_t* __restrict__ partial,
    const float* __restrict__ b3g, const float* __restrict__ b3s,
    ushort_t* __restrict__ hypb, float* __restrict__ y2, int KS)
{
  int b = blockIdx.x, br = blockIdx.y, d = threadIdx.x;
  const ushort_t* pp = partial + (long)(br * KS) * 64 * 256 + (long)b * 256 + d;
  float s = 0.f;
  #pragma unroll 8
  for (int ks = 0; ks < KS; ++ks) s += b2f(pp[(long)ks * 64 * 256]);
  s += (br ? b3s : b3g)[d];

  float v = s * s;
  #pragma unroll
  for (int off = 1; off < 64; off <<= 1) v += __shfl_xor(v, off);
  __shared__ float red[4];
  __shared__ float n2s;
  if ((threadIdx.x & 63) == 0) red[threadIdx.x >> 6] = v;
  __syncthreads();
  if (threadIdx.x == 0) n2s = red[0] + red[1] + red[2] + red[3];
  __syncthreads();
  float n = fmaxf(sqrtf(n2s), 1e-15f);
  float sn = SQRT_C * n;
  float t = tanhf(sn);
  float scale = t / sn;
  hypb[((long)br * 64 + b) * 256 + d] = f2bf(s * scale);
  if (threadIdx.x == 0) y2[br * 64 + b] = t * t / C_CURV;
}

// ---------------- Poincare distance logits (wave = 16 protos x 16 batch rows) ----------------
__global__ __launch_bounds__(256) void k_dist(const float* __restrict__ pg,
    const float* __restrict__ ps, const ushort_t* __restrict__ hypb,
    const float* __restrict__ y2, float* __restrict__ out)
{
  int u = blockIdx.x * 4 + (threadIdx.x >> 6);
  const int lane = threadIdx.x & 63;
  const int c = lane & 15, g = lane >> 4;
  const float* protos; const ushort_t* A; const float* y2p; float* ob; int P;
  if (u < 128) {
    protos = pg; P = 500; A = hypb; y2p = y2; ob = out;
  } else {
    u -= 128;
    if (u >= 1252) return;
    protos = ps; P = 5000; A = hypb + 64 * 256; y2p = y2 + 64; ob = out + 64 * 500;
  }
  const int w = u >> 2;    // proto tile
  const int mi = u & 3;    // 16-row slice of the batch
  int p = w * 16 + c;
  int pc = min(p, P - 1);
  const float* pp = protos + (long)pc * 256 + 8 * g;
  const ushort_t* ap = A + (long)(c + 16 * mi) * 256 + 8 * g;

  f32x4 acc = {0.f, 0.f, 0.f, 0.f};
  float x2p = 0.f;

  #pragma unroll
  for (int s8 = 0; s8 < 8; ++s8) {
    float4 v0 = *reinterpret_cast<const float4*>(pp + 32 * s8);
    float4 v1 = *reinterpret_cast<const float4*>(pp + 32 * s8 + 4);
    x2p += v0.x * v0.x + v0.y * v0.y + v0.z * v0.z + v0.w * v0.w
         + v1.x * v1.x + v1.y * v1.y + v1.z * v1.z + v1.w * v1.w;
    short8 bfr;
    bfr[0] = (short)f2bf(v0.x); bfr[1] = (short)f2bf(v0.y);
    bfr[2] = (short)f2bf(v0.z); bfr[3] = (short)f2bf(v0.w);
    bfr[4] = (short)f2bf(v1.x); bfr[5] = (short)f2bf(v1.y);
    bfr[6] = (short)f2bf(v1.z); bfr[7] = (short)f2bf(v1.w);
    short8 af = *reinterpret_cast<const short8*>(ap + 32 * s8);
    acc = __builtin_amdgcn_mfma_f32_16x16x32_bf16(af, bfr, acc, 0, 0, 0);
  }
  x2p += __shfl_xor(x2p, 16);
  x2p += __shfl_xor(x2p, 32);
  const float x2 = x2p;
  const float bb = 1.f - C_CURV * x2;
  const float LC = -2.f / (SQRT_C * TEMP_);

  if (p < P) {
    #pragma unroll
    for (int q = 0; q < 4; ++q) {
      int b = 16 * mi + 4 * g + q;
      float xy = -acc[q];
      float y2v = y2p[b];
      float a = 1.f + 2.f * C_CURV * xy + C_CURV * y2v;
      float den = fabsf(1.f + 2.f * C_CURV * xy + C_CURV * C_CURV * x2 * y2v);
      den = fmaxf(den, 1e-15f);
      float num2 = a * a * x2 + 2.f * a * bb * xy + bb * bb * y2v;
      num2 = fmaxf(num2, 0.f);
      float r = SQRT_C * sqrtf(num2) / den;
      r = fminf(r, 1.f - 1e-5f);
      r = fmaxf(r, 0.f);
      ob[(long)b * P + p] = LC * atanhf(r);
    }
  }
}

// ---------------- launch ----------------
extern "C" void kernel_launch(void* const* d_in, const int* in_sizes, int n_in,
                              void* d_out, int out_size, void* d_ws, size_t ws_size,
                              hipStream_t stream) {
  const float* x   = (const float*)d_in[0];
  const float* pg  = (const float*)d_in[1];
  const float* ps  = (const float*)d_in[2];
  const float* w1g = (const float*)d_in[3];
  const float* b1g = (const float*)d_in[4];
  const float* w2g = (const float*)d_in[5];
  const float* b2g = (const float*)d_in[6];
  const float* w3g = (const float*)d_in[7];
  const float* b3g = (const float*)d_in[8];
  const float* w1s = (const float*)d_in[9];
  const float* b1s = (const float*)d_in[10];
  const float* w2s = (const float*)d_in[11];
  const float* b2s = (const float*)d_in[12];
  const float* w3s = (const float*)d_in[13];
  const float* b3s = (const float*)d_in[14];
  float* out = (float*)d_out;
  char* ws = (char*)d_ws;
  (void)in_sizes; (void)n_in; (void)out_size; (void)ws_size;

  // K-splits: kchunk multiple of 32, nt = kchunk/32 >= 3.
  // L1: 768/8 = 96 (nt=3); L2: 4096/8 = 512 (nt=16); L3: 4096/32 = 128 (nt=4).
  const int KS1 = 8, KS2 = 8, KS3 = 32;
  // bf16 partials: max footprint = KS2*2*64*4096*2B = 8.39 MB
  size_t PART = (size_t)KS2 * 2 * 64 * 4096 * 2;

  ushort_t* partial = (ushort_t*)(ws);
  ushort_t* xb      = (ushort_t*)(ws + PART);
  ushort_t* h1b     = (ushort_t*)(ws + PART + 98304);
  ushort_t* h2b     = (ushort_t*)(ws + PART + 98304 + 1048576);
  ushort_t* hypb    = (ushort_t*)(ws + PART + 98304 + 2097152);
  float*    y2      = (float*)   (ws + PART + 98304 + 2097152 + 65536);

  // x -> bf16
  k_cvt_x<<<48, 256, 0, stream>>>(x, xb, 64 * 768 / 4);
  // layer 1: (64x768)@(768x4096), grid (4096/128, KS1, 2)
  k_gemm<<<dim3(32, KS1, 2), 512, 0, stream>>>(xb, 0L, w1g, w1s, partial, 4096, 768, 768 / KS1);
  k_reduce_gelu<<<256, 256, 0, stream>>>(partial, b1g, b1s, h1b, 4096, KS1, 2 * 64 * 4096 / 8);
  // layer 2: (64x4096)@(4096x4096)
  k_gemm<<<dim3(32, KS2, 2), 512, 0, stream>>>(h1b, (long)64 * 4096, w2g, w2s, partial, 4096, 4096, 4096 / KS2);
  k_reduce_gelu<<<256, 256, 0, stream>>>(partial, b2g, b2s, h2b, 4096, KS2, 2 * 64 * 4096 / 8);
  // layer 3: (64x4096)@(4096x256), grid (2, KS3, 2)
  k_gemm<<<dim3(2, KS3, 2), 512, 0, stream>>>(h2b, (long)64 * 4096, w3g, w3s, partial, 256, 4096, 4096 / KS3);
  // reduce + bias + expmap0 -> hyp bf16, y2
  k_expmap<<<dim3(64, 2), 256, 0, stream>>>(partial, b3g, b3s, hypb, y2, KS3);
  // poincare distances -> logits
  k_dist<<<345, 256, 0, stream>>>(pg, ps, hypb, y2, out);
}